// Round 2
// baseline (1410.507 us; speedup 1.0000x reference)
//
#include <hip/hip_runtime.h>
#include <hip/hip_bf16.h>
#include <math.h>

#define D_IN  128
#define D_OUT 64
#define RPB   16   // rows per bucket (packed as low 4 bits of pair)

// ---------------------------------------------------------------------------
// Edge-index dtype detection: reference declares int64, harness may pass int32.
// If buffer is little-endian int64 with values < 2^31, every odd u32 is 0.
// ---------------------------------------------------------------------------
__global__ void k_detect(const unsigned int* __restrict__ u, int* __restrict__ flag) {
    __shared__ int nonzero;
    if (threadIdx.x == 0) nonzero = 0;
    __syncthreads();
    if (u[2 * threadIdx.x + 1] != 0u) atomicOr(&nonzero, 1);
    __syncthreads();
    if (threadIdx.x == 0) *flag = (nonzero == 0) ? 1 : 0;  // 1 => int64
}

__device__ __forceinline__ int edge_val(const void* ei, int is64, long long idx) {
    return is64 ? (int)((const long long*)ei)[idx] : ((const int*)ei)[idx];
}

// ---------------------------------------------------------------------------
// Per-row degree count (edges only; +1 self loop added in k_dk)
// ---------------------------------------------------------------------------
__global__ void k_count(const void* __restrict__ ei, const int* __restrict__ flag,
                        int* __restrict__ cnt, long long E) {
    long long e = (long long)blockIdx.x * blockDim.x + threadIdx.x;
    if (e >= E) return;
    int is64 = *flag;
    int r = edge_val(ei, is64, e);
    atomicAdd(&cnt[r], 1);
}

// dk[i] = dinv[i]^k, deg = cnt+1 (self loop). k read on-device.
__global__ void k_dk(const int* __restrict__ cnt, const int* __restrict__ kptr,
                     float* __restrict__ dk, int n) {
    int i = blockIdx.x * blockDim.x + threadIdx.x;
    if (i >= n) return;
    int kk = kptr[0];
    if (kk < 0 || kk > 1000) {
        float kf = ((const float*)kptr)[0];
        kk = (kf > 0.f && kf < 1000.f) ? (int)(kf + 0.5f) : 2;
    }
    float deg = (float)(cnt[i] + 1);
    float dinv = 1.0f / sqrtf(deg);
    float v = 1.0f;
    for (int t = 0; t < kk; ++t) v *= dinv;
    dk[i] = v;
}

// ---------------------------------------------------------------------------
// Exclusive scan of cnt -> rowptr. CHUNK=1024, 3 kernels.
// ---------------------------------------------------------------------------
__global__ __launch_bounds__(256) void k_chunk_sum(const int* __restrict__ cnt,
                                                   int* __restrict__ csum, int n) {
    __shared__ int sm[256];
    int tid = threadIdx.x;
    int base = blockIdx.x * 1024 + tid * 4;
    int s = 0;
#pragma unroll
    for (int j = 0; j < 4; ++j) { int idx = base + j; if (idx < n) s += cnt[idx]; }
    sm[tid] = s; __syncthreads();
    for (int o = 128; o > 0; o >>= 1) { if (tid < o) sm[tid] += sm[tid + o]; __syncthreads(); }
    if (tid == 0) csum[blockIdx.x] = sm[0];
}

// single block; requires nchunks <= 128 (n=100000 -> 98)
__global__ void k_scan_chunks(const int* __restrict__ cs, int* __restrict__ co,
                              int* __restrict__ rowptr, int nchunks, int n) {
    __shared__ int sm[128];
    int tid = threadIdx.x;
    int v = (tid < nchunks) ? cs[tid] : 0;
    sm[tid] = v; __syncthreads();
    for (int o = 1; o < 128; o <<= 1) {
        int a = (tid >= o) ? sm[tid - o] : 0;
        __syncthreads();
        sm[tid] += a;
        __syncthreads();
    }
    if (tid < nchunks) co[tid] = sm[tid] - v;
    if (tid == 127) rowptr[n] = sm[127];
}

__global__ __launch_bounds__(256) void k_scan_final(const int* __restrict__ cnt,
        const int* __restrict__ coff, int* __restrict__ rowptr, int n) {
    __shared__ int sm[256];
    int tid = threadIdx.x;
    int base = blockIdx.x * 1024 + tid * 4;
    int v[4]; int t = 0;
#pragma unroll
    for (int j = 0; j < 4; ++j) { int idx = base + j; v[j] = (idx < n) ? cnt[idx] : 0; t += v[j]; }
    sm[tid] = t; __syncthreads();
    for (int o = 1; o < 256; o <<= 1) {
        int a = (tid >= o) ? sm[tid - o] : 0;
        __syncthreads();
        sm[tid] += a;
        __syncthreads();
    }
    int run = coff[blockIdx.x] + sm[tid] - t;
#pragma unroll
    for (int j = 0; j < 4; ++j) {
        int idx = base + j;
        if (idx < n) { rowptr[idx] = run; run += v[j]; }
    }
}

// bucket cursors (padded: 16 ints = 64B stride to avoid false sharing)
__global__ void k_bcur(const int* __restrict__ rowptr, int* __restrict__ bcur, int nb) {
    int b = blockIdx.x * blockDim.x + threadIdx.x;
    if (b < nb) bcur[b * 16] = rowptr[b * RPB];
}

// ---------------------------------------------------------------------------
// y2[r][:] = dk[r] * (x[r] @ W^T). 64 rows/block, 4x4 micro-tile per thread.
// ---------------------------------------------------------------------------
__global__ __launch_bounds__(256) void k_gemm(const float* __restrict__ x,
        const float* __restrict__ W, const float* __restrict__ dk,
        float* __restrict__ y2, int n) {
    __shared__ float Wt[D_IN][D_OUT];   // 32 KB
    __shared__ float xsT[D_IN][64];     // 32 KB
    const int tid = threadIdx.x;
    const int row0 = blockIdx.x * 64;

    {   // stage W transposed
        const int c = tid & 63;
        const int dblk = (tid >> 6) * 32;
        const float* wr = &W[c * D_IN + dblk];
#pragma unroll
        for (int j = 0; j < 32; j += 4) {
            float4 w4 = *(const float4*)(wr + j);
            Wt[dblk + j + 0][c] = w4.x;
            Wt[dblk + j + 1][c] = w4.y;
            Wt[dblk + j + 2][c] = w4.z;
            Wt[dblk + j + 3][c] = w4.w;
        }
    }
    {   // stage x rows transposed
        const int r = tid & 63;
        const int h = tid >> 6;
        const int grow = row0 + r;
        const float* xr = &x[(size_t)grow * D_IN + h * 32];
#pragma unroll
        for (int j = 0; j < 32; j += 4) {
            float4 v = (grow < n) ? *(const float4*)(xr + j)
                                  : make_float4(0.f, 0.f, 0.f, 0.f);
            xsT[h * 32 + j + 0][r] = v.x;
            xsT[h * 32 + j + 1][r] = v.y;
            xsT[h * 32 + j + 2][r] = v.z;
            xsT[h * 32 + j + 3][r] = v.w;
        }
    }
    __syncthreads();

    const int tx = tid & 15;
    const int ty = tid >> 4;
    float acc[4][4] = {};
#pragma unroll 8
    for (int d = 0; d < D_IN; ++d) {
        float4 wv = *(const float4*)&Wt[d][tx * 4];
        float4 xv = *(const float4*)&xsT[d][ty * 4];
        acc[0][0] += xv.x * wv.x; acc[0][1] += xv.x * wv.y; acc[0][2] += xv.x * wv.z; acc[0][3] += xv.x * wv.w;
        acc[1][0] += xv.y * wv.x; acc[1][1] += xv.y * wv.y; acc[1][2] += xv.y * wv.z; acc[1][3] += xv.y * wv.w;
        acc[2][0] += xv.z * wv.x; acc[2][1] += xv.z * wv.y; acc[2][2] += xv.z * wv.z; acc[2][3] += xv.z * wv.w;
        acc[3][0] += xv.w * wv.x; acc[3][1] += xv.w * wv.y; acc[3][2] += xv.w * wv.z; acc[3][3] += xv.w * wv.w;
    }
#pragma unroll
    for (int i = 0; i < 4; ++i) {
        int rr = row0 + ty * 4 + i;
        if (rr < n) {
            float s = dk[rr];
            float4 o = make_float4(acc[i][0] * s, acc[i][1] * s, acc[i][2] * s, acc[i][3] * s);
            *(float4*)&y2[(size_t)rr * D_OUT + tx * 4] = o;
        }
    }
}

// ---------------------------------------------------------------------------
// Bin edges into bucket-sorted packed pairs: pairs[p] = (col<<4) | (row&15).
// Append positions come from padded per-bucket atomic cursors -> writes to a
// bucket's region are quasi-sequential (good line utilization vs full CSR
// scatter which write-amplified 15x).
// ---------------------------------------------------------------------------
__global__ void k_binpairs(const void* __restrict__ ei, const int* __restrict__ flag,
                           int* __restrict__ bcur, unsigned int* __restrict__ pairs,
                           long long E) {
    long long e = (long long)blockIdx.x * blockDim.x + threadIdx.x;
    if (e >= E) return;
    int is64 = *flag;
    int r = edge_val(ei, is64, e);
    int c = edge_val(ei, is64, E + e);
    int b = r >> 4;                         // RPB = 16
    int p = atomicAdd(&bcur[b * 16], 1);
    pairs[p] = ((unsigned int)c << 4) | (unsigned int)(r & 15);
}

// ---------------------------------------------------------------------------
// Bucket SpMM: one workgroup per bucket of 16 rows. LDS accumulator
// acc[16][64] initialized from the y2 slab (self-loop term). 4 waves, each
// consuming 8 edges per step: gather y2[c][lane], ds_add into acc[lr][lane].
// Epilogue: out = dk[r]*acc + bias, coalesced float4 slab write.
// ---------------------------------------------------------------------------
__global__ __launch_bounds__(256) void k_bspmm(
        const int* __restrict__ rowptr, const unsigned int* __restrict__ pairs,
        const float* __restrict__ y2, const float* __restrict__ dk,
        const float* __restrict__ bias, float* __restrict__ out, int n) {
    __shared__ float acc[RPB * 64];         // 4 KB
    const int b   = blockIdx.x;
    const int r0  = b * RPB;
    const int rend = min(r0 + RPB, n);
    const int nr  = rend - r0;
    const int tid = threadIdx.x;

    {   // init acc = y2 slab (self-loop contribution)
        int f = tid * 4;
        if (f < nr * 64)
            *(float4*)&acc[f] = *(const float4*)&y2[(size_t)r0 * 64 + f];
    }
    __syncthreads();

    const int start = rowptr[r0];
    const int end   = rowptr[rend];
    const int wv    = tid >> 6;
    const int lane  = tid & 63;

    const int nfull = (end - start) >> 3;   // chunks of 8 edges
    for (int j = wv; j < nfull; j += 4) {
        int p = start + j * 8;
        unsigned int q[8];
#pragma unroll
        for (int jj = 0; jj < 8; ++jj) q[jj] = pairs[p + jj];
        float v[8];
#pragma unroll
        for (int jj = 0; jj < 8; ++jj)
            v[jj] = y2[(size_t)(q[jj] >> 4) * 64 + lane];
#pragma unroll
        for (int jj = 0; jj < 8; ++jj)
            atomicAdd(&acc[(q[jj] & 15u) * 64 + lane], v[jj]);
    }
    for (int p = start + nfull * 8 + wv; p < end; p += 4) {
        unsigned int q = pairs[p];
        float v = y2[(size_t)(q >> 4) * 64 + lane];
        atomicAdd(&acc[(q & 15u) * 64 + lane], v);
    }
    __syncthreads();

    {   // epilogue
        int f = tid * 4;
        if (f < nr * 64) {
            int r = r0 + (f >> 6);
            float s = dk[r];
            float4 a = *(float4*)&acc[f];
            float4 bb = *(const float4*)&bias[f & 63];
            float4 o = make_float4(s * a.x + bb.x, s * a.y + bb.y,
                                   s * a.z + bb.z, s * a.w + bb.w);
            *(float4*)&out[(size_t)r0 * 64 + f] = o;
        }
    }
}

// ---------------------------------------------------------------------------
extern "C" void kernel_launch(void* const* d_in, const int* in_sizes, int n_in,
                              void* d_out, int out_size, void* d_ws, size_t ws_size,
                              hipStream_t stream) {
    const float* x    = (const float*)d_in[0];
    const void*  ei   = d_in[1];
    const float* W    = (const float*)d_in[2];
    const float* b    = (const float*)d_in[3];
    const int*   kptr = (const int*)d_in[4];

    const int       n = in_sizes[0] / D_IN;            // 100000
    const long long E = (long long)in_sizes[1] / 2;    // 3200000
    const int      nb = (n + RPB - 1) / RPB;           // 6250 buckets

    char* ws = (char*)d_ws;
    size_t off = 0;
    auto alloc = [&](size_t bytes) -> void* {
        void* p = ws + off;
        off += (bytes + 255) & ~(size_t)255;
        return p;
    };
    int*          flag   = (int*)alloc(4);
    int*          cnt    = (int*)alloc((size_t)n * 4);
    int*          rowptr = (int*)alloc(((size_t)n + 1) * 4);
    float*        dk     = (float*)alloc((size_t)n * 4);
    int*          csum   = (int*)alloc(128 * 4);
    int*          coff   = (int*)alloc(128 * 4);
    int*          bcur   = (int*)alloc((size_t)nb * 16 * 4);   // 64B-padded cursors
    float*        y2     = (float*)alloc((size_t)n * D_OUT * 4);
    unsigned int* pairs  = (unsigned int*)alloc((size_t)E * 4);
    (void)ws_size; (void)n_in; (void)out_size;

    const int eb = (int)((E + 255) / 256);
    const int nchunks = (n + 1023) / 1024;             // 98 (<=128 required)

    hipMemsetAsync(cnt, 0, (size_t)n * 4, stream);
    k_detect<<<1, 256, 0, stream>>>((const unsigned int*)ei, flag);
    k_count<<<eb, 256, 0, stream>>>(ei, flag, cnt, E);
    k_dk<<<(n + 255) / 256, 256, 0, stream>>>(cnt, kptr, dk, n);
    k_chunk_sum<<<nchunks, 256, 0, stream>>>(cnt, csum, n);
    k_scan_chunks<<<1, 128, 0, stream>>>(csum, coff, rowptr, nchunks, n);
    k_scan_final<<<nchunks, 256, 0, stream>>>(cnt, coff, rowptr, n);
    k_bcur<<<(nb + 255) / 256, 256, 0, stream>>>(rowptr, bcur, nb);
    k_gemm<<<(n + 63) / 64, 256, 0, stream>>>(x, W, dk, y2, n);
    k_binpairs<<<eb, 256, 0, stream>>>(ei, flag, bcur, pairs, E);
    k_bspmm<<<nb, 256, 0, stream>>>(rowptr, pairs, y2, dk, b, (float*)d_out, n);
}

// Round 3
// 447.940 us; speedup vs baseline: 3.1489x; 3.1489x over previous
//
#include <hip/hip_runtime.h>
#include <hip/hip_bf16.h>
#include <math.h>

#define D_IN  128
#define D_OUT 64
#define NGRP  8     // row-range groups, matched to 8 XCDs via blockIdx&7

// ---------------------------------------------------------------------------
// Edge-index dtype detection: reference declares int64, harness may pass int32.
// If buffer is little-endian int64 with values < 2^31, every odd u32 is 0.
// ---------------------------------------------------------------------------
__global__ void k_detect(const unsigned int* __restrict__ u, int* __restrict__ flag) {
    __shared__ int nonzero;
    if (threadIdx.x == 0) nonzero = 0;
    __syncthreads();
    if (u[2 * threadIdx.x + 1] != 0u) atomicOr(&nonzero, 1);
    __syncthreads();
    if (threadIdx.x == 0) *flag = (nonzero == 0) ? 1 : 0;  // 1 => int64
}

__device__ __forceinline__ int edge_val(const void* ei, int is64, long long idx) {
    return is64 ? (int)((const long long*)ei)[idx] : ((const int*)ei)[idx];
}

// ---------------------------------------------------------------------------
// XCD-grouped degree count. Blocks with blockIdx&7==g sweep ALL edges but
// count only rows in [g*n/8,(g+1)*n/8) -> cnt lines stay in ONE XCD's L2
// (assuming round-robin block->XCD; correctness independent of mapping).
// ---------------------------------------------------------------------------
__global__ __launch_bounds__(256) void k_count_f(const void* __restrict__ ei,
        const int* __restrict__ flag, int* __restrict__ cnt, long long E, int n) {
    const int g  = blockIdx.x & (NGRP - 1);
    const int lo = (int)(((long long)n * g) >> 3);
    const int hi = (int)(((long long)n * (g + 1)) >> 3);
    const int is64 = *flag;
    const long long stride = (long long)(gridDim.x >> 3) * blockDim.x;
    long long e = (long long)(blockIdx.x >> 3) * blockDim.x + threadIdx.x;
    for (; e < E; e += stride) {
        int r = edge_val(ei, is64, e);
        if (r >= lo && r < hi) atomicAdd(&cnt[r], 1);
    }
}

// dk[i] = dinv[i]^k, deg = cnt+1 (self loop). k read on-device.
__global__ void k_dk(const int* __restrict__ cnt, const int* __restrict__ kptr,
                     float* __restrict__ dk, int n) {
    int i = blockIdx.x * blockDim.x + threadIdx.x;
    if (i >= n) return;
    int kk = kptr[0];
    if (kk < 0 || kk > 1000) {
        float kf = ((const float*)kptr)[0];
        kk = (kf > 0.f && kf < 1000.f) ? (int)(kf + 0.5f) : 2;
    }
    float deg = (float)(cnt[i] + 1);
    float dinv = 1.0f / sqrtf(deg);
    float v = 1.0f;
    for (int t = 0; t < kk; ++t) v *= dinv;
    dk[i] = v;
}

// ---------------------------------------------------------------------------
// Exclusive scan of cnt -> rowptr (+cursor copy). CHUNK=1024, 3 kernels.
// ---------------------------------------------------------------------------
__global__ __launch_bounds__(256) void k_chunk_sum(const int* __restrict__ cnt,
                                                   int* __restrict__ csum, int n) {
    __shared__ int sm[256];
    int tid = threadIdx.x;
    int base = blockIdx.x * 1024 + tid * 4;
    int s = 0;
#pragma unroll
    for (int j = 0; j < 4; ++j) { int idx = base + j; if (idx < n) s += cnt[idx]; }
    sm[tid] = s; __syncthreads();
    for (int o = 128; o > 0; o >>= 1) { if (tid < o) sm[tid] += sm[tid + o]; __syncthreads(); }
    if (tid == 0) csum[blockIdx.x] = sm[0];
}

// single block; requires nchunks <= 128 (n=100000 -> 98)
__global__ void k_scan_chunks(const int* __restrict__ cs, int* __restrict__ co,
                              int* __restrict__ rowptr, int nchunks, int n) {
    __shared__ int sm[128];
    int tid = threadIdx.x;
    int v = (tid < nchunks) ? cs[tid] : 0;
    sm[tid] = v; __syncthreads();
    for (int o = 1; o < 128; o <<= 1) {
        int a = (tid >= o) ? sm[tid - o] : 0;
        __syncthreads();
        sm[tid] += a;
        __syncthreads();
    }
    if (tid < nchunks) co[tid] = sm[tid] - v;
    if (tid == 127) rowptr[n] = sm[127];
}

__global__ __launch_bounds__(256) void k_scan_final(const int* __restrict__ cnt,
        const int* __restrict__ coff, int* __restrict__ rowptr,
        int* __restrict__ cursor, int n) {
    __shared__ int sm[256];
    int tid = threadIdx.x;
    int base = blockIdx.x * 1024 + tid * 4;
    int v[4]; int t = 0;
#pragma unroll
    for (int j = 0; j < 4; ++j) { int idx = base + j; v[j] = (idx < n) ? cnt[idx] : 0; t += v[j]; }
    sm[tid] = t; __syncthreads();
    for (int o = 1; o < 256; o <<= 1) {
        int a = (tid >= o) ? sm[tid - o] : 0;
        __syncthreads();
        sm[tid] += a;
        __syncthreads();
    }
    int run = coff[blockIdx.x] + sm[tid] - t;
#pragma unroll
    for (int j = 0; j < 4; ++j) {
        int idx = base + j;
        if (idx < n) { rowptr[idx] = run; cursor[idx] = run; run += v[j]; }
    }
}

// ---------------------------------------------------------------------------
// y2[r][:] = dk[r] * (x[r] @ W^T). 64 rows/block, 4x4 micro-tile per thread.
// ---------------------------------------------------------------------------
__global__ __launch_bounds__(256) void k_gemm(const float* __restrict__ x,
        const float* __restrict__ W, const float* __restrict__ dk,
        float* __restrict__ y2, int n) {
    __shared__ float Wt[D_IN][D_OUT];   // 32 KB
    __shared__ float xsT[D_IN][64];     // 32 KB
    const int tid = threadIdx.x;
    const int row0 = blockIdx.x * 64;

    {   // stage W transposed
        const int c = tid & 63;
        const int dblk = (tid >> 6) * 32;
        const float* wr = &W[c * D_IN + dblk];
#pragma unroll
        for (int j = 0; j < 32; j += 4) {
            float4 w4 = *(const float4*)(wr + j);
            Wt[dblk + j + 0][c] = w4.x;
            Wt[dblk + j + 1][c] = w4.y;
            Wt[dblk + j + 2][c] = w4.z;
            Wt[dblk + j + 3][c] = w4.w;
        }
    }
    {   // stage x rows transposed
        const int r = tid & 63;
        const int h = tid >> 6;
        const int grow = row0 + r;
        const float* xr = &x[(size_t)grow * D_IN + h * 32];
#pragma unroll
        for (int j = 0; j < 32; j += 4) {
            float4 v = (grow < n) ? *(const float4*)(xr + j)
                                  : make_float4(0.f, 0.f, 0.f, 0.f);
            xsT[h * 32 + j + 0][r] = v.x;
            xsT[h * 32 + j + 1][r] = v.y;
            xsT[h * 32 + j + 2][r] = v.z;
            xsT[h * 32 + j + 3][r] = v.w;
        }
    }
    __syncthreads();

    const int tx = tid & 15;
    const int ty = tid >> 4;
    float acc[4][4] = {};
#pragma unroll 8
    for (int d = 0; d < D_IN; ++d) {
        float4 wv = *(const float4*)&Wt[d][tx * 4];
        float4 xv = *(const float4*)&xsT[d][ty * 4];
        acc[0][0] += xv.x * wv.x; acc[0][1] += xv.x * wv.y; acc[0][2] += xv.x * wv.z; acc[0][3] += xv.x * wv.w;
        acc[1][0] += xv.y * wv.x; acc[1][1] += xv.y * wv.y; acc[1][2] += xv.y * wv.z; acc[1][3] += xv.y * wv.w;
        acc[2][0] += xv.z * wv.x; acc[2][1] += xv.z * wv.y; acc[2][2] += xv.z * wv.z; acc[2][3] += xv.z * wv.w;
        acc[3][0] += xv.w * wv.x; acc[3][1] += xv.w * wv.y; acc[3][2] += xv.w * wv.z; acc[3][3] += xv.w * wv.w;
    }
#pragma unroll
    for (int i = 0; i < 4; ++i) {
        int rr = row0 + ty * 4 + i;
        if (rr < n) {
            float s = dk[rr];
            float4 o = make_float4(acc[i][0] * s, acc[i][1] * s, acc[i][2] * s, acc[i][3] * s);
            *(float4*)&y2[(size_t)rr * D_OUT + tx * 4] = o;
        }
    }
}

// ---------------------------------------------------------------------------
// XCD-grouped CSR colidx build. Same grouping as k_count_f: cursor atomics
// and colidx writes for a row-range come from one group (-> one XCD's L2).
// ---------------------------------------------------------------------------
__global__ __launch_bounds__(256) void k_scatter_f(const void* __restrict__ ei,
        const int* __restrict__ flag, int* __restrict__ cursor,
        int* __restrict__ colidx, long long E, int n) {
    const int g  = blockIdx.x & (NGRP - 1);
    const int lo = (int)(((long long)n * g) >> 3);
    const int hi = (int)(((long long)n * (g + 1)) >> 3);
    const int is64 = *flag;
    const long long stride = (long long)(gridDim.x >> 3) * blockDim.x;
    long long e = (long long)(blockIdx.x >> 3) * blockDim.x + threadIdx.x;
    for (; e < E; e += stride) {
        int r = edge_val(ei, is64, e);
        if (r >= lo && r < hi) {
            int c = edge_val(ei, is64, E + e);
            int p = atomicAdd(&cursor[r], 1);
            colidx[p] = c;
        }
    }
}

// ---------------------------------------------------------------------------
// SpMM: one wave per row, lane = output feature (D_OUT == 64 == wave size).
// out[i] = dk[i] * (y2[i] + sum_e y2[col_e]) + b
// ---------------------------------------------------------------------------
__global__ __launch_bounds__(256) void k_spmm(
        const int* __restrict__ rowptr, const int* __restrict__ colidx,
        const float* __restrict__ y2, const float* __restrict__ dk,
        const float* __restrict__ bias, float* __restrict__ out, int n) {
    int wid  = (int)((blockIdx.x * (long long)blockDim.x + threadIdx.x) >> 6);
    int lane = threadIdx.x & 63;
    if (wid >= n) return;

    int start = rowptr[wid];
    int end   = rowptr[wid + 1];
    float acc = y2[(size_t)wid * D_OUT + lane];   // self loop term

    int e = start;
    for (; e + 8 <= end; e += 8) {
        int c0 = colidx[e + 0], c1 = colidx[e + 1], c2 = colidx[e + 2], c3 = colidx[e + 3];
        int c4 = colidx[e + 4], c5 = colidx[e + 5], c6 = colidx[e + 6], c7 = colidx[e + 7];
        float v0 = y2[(size_t)c0 * D_OUT + lane];
        float v1 = y2[(size_t)c1 * D_OUT + lane];
        float v2 = y2[(size_t)c2 * D_OUT + lane];
        float v3 = y2[(size_t)c3 * D_OUT + lane];
        float v4 = y2[(size_t)c4 * D_OUT + lane];
        float v5 = y2[(size_t)c5 * D_OUT + lane];
        float v6 = y2[(size_t)c6 * D_OUT + lane];
        float v7 = y2[(size_t)c7 * D_OUT + lane];
        acc += ((v0 + v1) + (v2 + v3)) + ((v4 + v5) + (v6 + v7));
    }
    for (; e < end; ++e)
        acc += y2[(size_t)colidx[e] * D_OUT + lane];

    out[(size_t)wid * D_OUT + lane] = dk[wid] * acc + bias[lane];
}

// ---------------------------------------------------------------------------
extern "C" void kernel_launch(void* const* d_in, const int* in_sizes, int n_in,
                              void* d_out, int out_size, void* d_ws, size_t ws_size,
                              hipStream_t stream) {
    const float* x    = (const float*)d_in[0];
    const void*  ei   = d_in[1];
    const float* W    = (const float*)d_in[2];
    const float* b    = (const float*)d_in[3];
    const int*   kptr = (const int*)d_in[4];

    const int       n = in_sizes[0] / D_IN;            // 100000
    const long long E = (long long)in_sizes[1] / 2;    // 3200000

    char* ws = (char*)d_ws;
    size_t off = 0;
    auto alloc = [&](size_t bytes) -> void* {
        void* p = ws + off;
        off += (bytes + 255) & ~(size_t)255;
        return p;
    };
    int*   flag   = (int*)alloc(4);
    int*   cnt    = (int*)alloc((size_t)n * 4);
    int*   rowptr = (int*)alloc(((size_t)n + 1) * 4);
    int*   cursor = (int*)alloc((size_t)n * 4);
    float* dk     = (float*)alloc((size_t)n * 4);
    int*   csum   = (int*)alloc(128 * 4);
    int*   coff   = (int*)alloc(128 * 4);
    float* y2     = (float*)alloc((size_t)n * D_OUT * 4);
    int*   colidx = (int*)alloc((size_t)E * 4);
    (void)ws_size; (void)n_in; (void)out_size;

    const int nchunks = (n + 1023) / 1024;             // 98 (<=128 required)
    const int fblocks = 2048;                          // multiple of 8; ~8 wg/CU

    hipMemsetAsync(cnt, 0, (size_t)n * 4, stream);
    k_detect<<<1, 256, 0, stream>>>((const unsigned int*)ei, flag);
    k_count_f<<<fblocks, 256, 0, stream>>>(ei, flag, cnt, E, n);
    k_dk<<<(n + 255) / 256, 256, 0, stream>>>(cnt, kptr, dk, n);
    k_chunk_sum<<<nchunks, 256, 0, stream>>>(cnt, csum, n);
    k_scan_chunks<<<1, 128, 0, stream>>>(csum, coff, rowptr, nchunks, n);
    k_scan_final<<<nchunks, 256, 0, stream>>>(cnt, coff, rowptr, cursor, n);
    k_gemm<<<(n + 63) / 64, 256, 0, stream>>>(x, W, dk, y2, n);
    k_scatter_f<<<fblocks, 256, 0, stream>>>(ei, flag, cursor, colidx, E, n);
    k_spmm<<<(n + 3) / 4, 256, 0, stream>>>(rowptr, colidx, y2, dk, b, (float*)d_out, n);
}